// Round 1
// baseline (133.860 us; speedup 1.0000x reference)
//
#include <hip/hip_runtime.h>

// Problem constants (B,V,T,H,W) = (32, 8, 2, 192, 288)
#define D        16        // V*T
#define NPAIR    136       // D*(D+1)/2 upper-triangle Gram entries
#define NVALS    152       // NPAIR + D row sums
#define HW       55296     // H*W
#define BSTRIDE  884736    // V*T*H*W (batch stride in floats)
#define NTOT     1769472   // B*H*W = N
#define NQUADS   442368    // NTOT / 4
#define NBLK     512       // blocks for kernel 1
#define QPB      864       // NQUADS / NBLK (exact)
#define QPERB    13824     // HW / 4 (quads per batch-slab)

// Pass 1: per-block partial uncentered Gram (upper triangle) + row sums.
// part layout (transposed for the reducer): part[i * NBLK + blockIdx.x]
__global__ __launch_bounds__(256, 1)
void gram_partial(const float* __restrict__ yt, const float* __restrict__ yp,
                  float* __restrict__ part) {
    float acc[NPAIR];
    float sums[D];
#pragma unroll
    for (int i = 0; i < NPAIR; ++i) acc[i] = 0.0f;
#pragma unroll
    for (int i = 0; i < D; ++i) sums[i] = 0.0f;

    const int q0 = blockIdx.x * QPB;
    for (int t = threadIdx.x; t < QPB; t += 256) {
        const int q   = q0 + t;
        const int b   = q / QPERB;          // batch index
        const int hw4 = q - b * QPERB;      // quad index within (b) plane
        const int base = b * BSTRIDE + hw4 * 4;

        float4 r[D];
#pragma unroll
        for (int d = 0; d < D; ++d) {
            const float4 a = *reinterpret_cast<const float4*>(yt + base + d * HW);
            const float4 p = *reinterpret_cast<const float4*>(yp + base + d * HW);
            r[d] = make_float4(a.x - p.x, a.y - p.y, a.z - p.z, a.w - p.w);
        }
#pragma unroll
        for (int d = 0; d < D; ++d)
            sums[d] += (r[d].x + r[d].y) + (r[d].z + r[d].w);

        int idx = 0;
#pragma unroll
        for (int d = 0; d < D; ++d) {
#pragma unroll
            for (int e = d; e < D; ++e) {
                acc[idx] += r[d].x * r[e].x + r[d].y * r[e].y
                          + r[d].z * r[e].z + r[d].w * r[e].w;
                ++idx;
            }
        }
    }

    // Block reduction: wave shuffle (64 lanes) then cross-wave via LDS.
    __shared__ float lds[4][NVALS];
    const int lane = threadIdx.x & 63;
    const int wv   = threadIdx.x >> 6;
#pragma unroll
    for (int i = 0; i < NVALS; ++i) {
        float v = (i < NPAIR) ? acc[i] : sums[i - NPAIR];
        v += __shfl_down(v, 32);
        v += __shfl_down(v, 16);
        v += __shfl_down(v, 8);
        v += __shfl_down(v, 4);
        v += __shfl_down(v, 2);
        v += __shfl_down(v, 1);
        if (lane == 0) lds[wv][i] = v;
    }
    __syncthreads();
    for (int i = threadIdx.x; i < NVALS; i += 256) {
        part[i * NBLK + blockIdx.x] =
            (lds[0][i] + lds[1][i]) + (lds[2][i] + lds[3][i]);
    }
}

__device__ __forceinline__ int tri_idx(int d, int e) {
    // d <= e required
    return d * D - (d * (d - 1)) / 2 + (e - d);
}

// Pass 2 (single block, 256 threads): reduce partials, build cov, invert
// 16x16 via cooperative Gauss-Jordan, emit (1/N) * sum(P .* S).
__global__ void finalize_kernel(const float* __restrict__ part,
                                float* __restrict__ out) {
    __shared__ float S[NVALS];
    __shared__ float A[D][2 * D + 1];   // [cov | I], padded row

    const int tid  = threadIdx.x;
    const int lane = tid & 63;
    const int wv   = tid >> 6;

    // 1) Reduce 512 block-partials: one wave per value, coalesced loads.
    for (int i = wv; i < NVALS; i += 4) {
        float s = 0.0f;
#pragma unroll
        for (int j = 0; j < NBLK / 64; ++j)
            s += part[i * NBLK + j * 64 + lane];
        s += __shfl_down(s, 32);
        s += __shfl_down(s, 16);
        s += __shfl_down(s, 8);
        s += __shfl_down(s, 4);
        s += __shfl_down(s, 2);
        s += __shfl_down(s, 1);
        if (lane == 0) S[i] = s;
    }
    __syncthreads();

    // 2) Augmented matrix [cov | I]
    {
        const int d = tid >> 4, e = tid & 15;
        const int lo = d < e ? d : e, hi = d < e ? e : d;
        const float invN = 1.0f / (float)NTOT;
        const float cov = (S[tri_idx(lo, hi)] -
                           S[NPAIR + d] * S[NPAIR + e] * invN) /
                          (float)(NTOT - 1);
        A[d][e]     = cov;
        A[d][D + e] = (d == e) ? 1.0f : 0.0f;
    }
    __syncthreads();

    // 3) Gauss-Jordan (no pivoting; cov ~ 0.01*I, well-conditioned).
    const int r0 = tid >> 5;   // 0..7
    const int c0 = tid & 31;   // 0..31
    const int r1 = r0 + 8;
    for (int k = 0; k < D; ++k) {
        const float pivinv = 1.0f / A[k][k];
        __syncthreads();
        if (tid < 32) A[k][tid] *= pivinv;
        __syncthreads();
        const float f0 = A[r0][k];
        const float f1 = A[r1][k];
        __syncthreads();
        const float akc = A[k][c0];
        if (r0 != k) A[r0][c0] -= f0 * akc;
        if (r1 != k) A[r1][c0] -= f1 * akc;
        __syncthreads();
    }

    // 4) result = (1/N) * sum_{d,e} P[d][e] * S[d][e]
    float term;
    {
        const int d = tid >> 4, e = tid & 15;
        const int lo = d < e ? d : e, hi = d < e ? e : d;
        float p = A[d][D + e];
        const float scale = 1.0f;  // OFF_DIAGONAL_SCALE
        if (d != e) p *= scale;
        term = p * S[tri_idx(lo, hi)];
    }
    term += __shfl_down(term, 32);
    term += __shfl_down(term, 16);
    term += __shfl_down(term, 8);
    term += __shfl_down(term, 4);
    term += __shfl_down(term, 2);
    term += __shfl_down(term, 1);

    __shared__ float wsum[4];
    if (lane == 0) wsum[wv] = term;
    __syncthreads();
    if (tid == 0) {
        const float tot = (wsum[0] + wsum[1]) + (wsum[2] + wsum[3]);
        out[0] = tot / (float)NTOT;
    }
}

extern "C" void kernel_launch(void* const* d_in, const int* in_sizes, int n_in,
                              void* d_out, int out_size, void* d_ws, size_t ws_size,
                              hipStream_t stream) {
    const float* y_true = (const float*)d_in[0];
    const float* y_pred = (const float*)d_in[1];
    float* out  = (float*)d_out;
    float* part = (float*)d_ws;   // needs NVALS * NBLK * 4 = 311,296 bytes

    hipLaunchKernelGGL(gram_partial, dim3(NBLK), dim3(256), 0, stream,
                       y_true, y_pred, part);
    hipLaunchKernelGGL(finalize_kernel, dim3(1), dim3(256), 0, stream,
                       part, out);
}